// Round 9
// baseline (193.972 us; speedup 1.0000x reference)
//
#include <hip/hip_runtime.h>

typedef _Float16 f16x8 __attribute__((ext_vector_type(8)));
typedef float    f32x4 __attribute__((ext_vector_type(4)));

#define N_ROWS 8192
#define DIM 64
#define EPS 1e-8f
#define LOG2E 1.4426950408889634f
#define SHIFT 64.0f                      // exp terms scaled by 2^64
#define SHIFT_LN 44.361419555836499802f  // 64 * ln(2)
#define PANEL 512                        // i-panel (8 waves x 64 rows, mt=4)
#define NPAN (N_ROWS / PANEL)            // 16 panels
#define MAXC 9                           // max j-chunks (16 rows) per block
#define TB 491                           // sum_p ceil(32(p+1)/9) -> one round

// ws: top[8192] | bot[8192] | sq[8192] (f32) | xh[8192*64] | xl[8192*64] (f16)

// fused: zero top/bot/out + f16 split + row norms. one wave per row.
__global__ void snn_prep(const float* __restrict__ x, _Float16* __restrict__ xh,
                         _Float16* __restrict__ xl, float* __restrict__ sq,
                         float* __restrict__ top, float* __restrict__ bot,
                         float* __restrict__ out) {
    const int gt = blockIdx.x * 256 + threadIdx.x;
    if (gt < N_ROWS) { top[gt] = 0.0f; bot[gt] = 0.0f; }
    if (gt == 0) out[0] = 0.0f;
    const int row = gt >> 6, lane = threadIdx.x & 63;
    float v = x[row * DIM + lane];
    _Float16 h = (_Float16)v;
    _Float16 l = (_Float16)(v - (float)h);
    xh[row * DIM + lane] = h;
    xl[row * DIM + lane] = l;
    float s = v * v;
    #pragma unroll
    for (int off = 32; off > 0; off >>= 1) s += __shfl_xor(s, off, 64);
    if (lane == 0) sq[row] = s;
}

// Symmetric triangular pass, 8-wave blocks (512-row i-panels).
// R8 confirmed the round-quantization model (T = rounds * NT * t_nt, 5
// structures within 2%) and showed 44% issue-busy at 2 waves/SIMD. This
// round doubles TLP at the SAME VGPR cap: 512-thread blocks, (512,4) ->
// cap 128 (use ~96), 2 blocks/CU = 4 waves/SIMD. Partition: panel p
// (512 rows) split into ceil(32(p+1)/9) blocks of <=9 16-row j-chunks;
// 491 blocks <= 512 slots -> still ONE scheduling round, makespan 9 chunks.
// Sub-diagonal chunks (j < 512p) accumulate both sides; the 32 diagonal
// chunks are one-sided with i!=j guard (square visits both orders).
__global__ __launch_bounds__(512, 4) void snn_mfma(
    const _Float16* __restrict__ xh, const _Float16* __restrict__ xl,
    const float* __restrict__ sq, const int* __restrict__ y,
    const float* __restrict__ w,
    float* __restrict__ top, float* __restrict__ bot)
{
    __shared__ float s_sqj[MAXC * 16];
    __shared__ int   s_yj[MAXC * 16];
    __shared__ float s_jt[8][MAXC * 16];   // per-wave col-side top (no atomics)
    __shared__ float s_jb[8][MAXC * 16];   // per-wave col-side bot

    // ---- decode bid -> (panel p, local chunk range [lc0, lc0+len)) ----
    const int bid = blockIdx.x;
    int p = 0, kk = 0, cum = 0;
    for (int q = 0; q < NPAN; q++) {
        int nb = (32 * (q + 1) + MAXC - 1) / MAXC;   // ceil
        if (bid < cum + nb) { p = q; kk = bid - cum; break; }
        cum += nb;
    }
    const int nchunks = 32 * (p + 1);      // panel covers j-chunks [0, nchunks)
    const int lc0 = kk * MAXC;             // first chunk of this block
    const int len = min(MAXC, nchunks - lc0);
    const int ndch = min(max(32 * p - lc0, 0), len);  // leading both-sided chunks
    const int I0 = p * PANEL;

    const int tid = threadIdx.x, wv = tid >> 6, lane = tid & 63;
    const int mrow = lane & 15, kq = lane >> 4;

    for (int t = tid; t < len * 16; t += 512) {
        s_sqj[t] = sq[lc0 * 16 + t];
        s_yj[t]  = y[lc0 * 16 + t];
    }
    __syncthreads();

    const int iw = I0 + wv * 64;   // this wave's first i-row

    // A fragments resident for the block lifetime
    f16x8 ah[4][2], al[4][2];
    #pragma unroll
    for (int mt = 0; mt < 4; mt++)
        #pragma unroll
        for (int kc = 0; kc < 2; kc++) {
            int a = (iw + mt * 16 + mrow) * DIM + kc * 32 + kq * 8;
            ah[mt][kc] = *(const f16x8*)(xh + a);
            al[mt][kc] = *(const f16x8*)(xl + a);
        }

    // per-slot row metadata: i = iw + mt*16 + kq*4 + rr ; labels packed 4/VGPR
    float sqi[4][4]; int ypack[4];
    #pragma unroll
    for (int mt = 0; mt < 4; mt++) {
        int yp = 0;
        #pragma unroll
        for (int rr = 0; rr < 4; rr++) {
            int i = iw + mt * 16 + kq * 4 + rr;
            sqi[mt][rr] = sq[i];
            yp |= (y[i] & 255) << (8 * rr);
        }
        ypack[mt] = yp;
    }

    float ts[4][4], bs[4][4];
    #pragma unroll
    for (int mt = 0; mt < 4; mt++)
        #pragma unroll
        for (int rr = 0; rr < 4; rr++) { ts[mt][rr] = 0.0f; bs[mt][rr] = 0.0f; }

    const float c1 = -w[0] * LOG2E;

#define LOAD_B_AND_MFMA()                                                        \
    const int jr = (lc0 + ntl) * 16 + mrow;       /* this lane's global j row */ \
    const int boff = jr * DIM + kq * 8;                                          \
    f16x8 cbh0 = *(const f16x8*)(xh + boff);                                     \
    f16x8 cbh1 = *(const f16x8*)(xh + boff + 32);                                \
    f16x8 cbl0 = *(const f16x8*)(xl + boff);                                     \
    f16x8 cbl1 = *(const f16x8*)(xl + boff + 32);                                \
    const float sqj = s_sqj[ntl * 16 + mrow];                                    \
    const int   yj  = s_yj[ntl * 16 + mrow];                                     \
    f32x4 acc[4];                                                                \
    _Pragma("unroll")                                                            \
    for (int mt = 0; mt < 4; mt++) acc[mt] = (f32x4){0.f, 0.f, 0.f, 0.f};        \
    _Pragma("unroll")                                                            \
    for (int mt = 0; mt < 4; mt++)                                               \
        acc[mt] = __builtin_amdgcn_mfma_f32_16x16x32_f16(ah[mt][0], cbh0, acc[mt], 0, 0, 0); \
    _Pragma("unroll")                                                            \
    for (int mt = 0; mt < 4; mt++)                                               \
        acc[mt] = __builtin_amdgcn_mfma_f32_16x16x32_f16(ah[mt][1], cbh1, acc[mt], 0, 0, 0); \
    _Pragma("unroll")                                                            \
    for (int mt = 0; mt < 4; mt++)                                               \
        acc[mt] = __builtin_amdgcn_mfma_f32_16x16x32_f16(ah[mt][0], cbl0, acc[mt], 0, 0, 0); \
    _Pragma("unroll")                                                            \
    for (int mt = 0; mt < 4; mt++)                                               \
        acc[mt] = __builtin_amdgcn_mfma_f32_16x16x32_f16(ah[mt][1], cbl1, acc[mt], 0, 0, 0); \
    _Pragma("unroll")                                                            \
    for (int mt = 0; mt < 4; mt++)                                               \
        acc[mt] = __builtin_amdgcn_mfma_f32_16x16x32_f16(al[mt][0], cbh0, acc[mt], 0, 0, 0); \
    _Pragma("unroll")                                                            \
    for (int mt = 0; mt < 4; mt++)                                               \
        acc[mt] = __builtin_amdgcn_mfma_f32_16x16x32_f16(al[mt][1], cbh1, acc[mt], 0, 0, 0);

    // ---- loop 1: sub-diagonal chunks, both-sided, i != j guaranteed ----
    for (int ntl = 0; ntl < ndch; ntl++) {
        LOAD_B_AND_MFMA()
        float jt = 0.0f, jb = 0.0f;
        #pragma unroll
        for (int mt = 0; mt < 4; mt++)
            #pragma unroll
            for (int rr = 0; rr < 4; rr++) {
                float d2 = fmaf(-2.0f, acc[mt][rr], sqi[mt][rr] + sqj);
                d2 = fmaxf(d2, 0.0f);
                float dist = __builtin_amdgcn_sqrtf(d2);
                float e2 = __builtin_amdgcn_exp2f(fmaf(c1, dist, SHIFT));
                float e2t = (yj == ((ypack[mt] >> (8 * rr)) & 255)) ? e2 : 0.0f;
                ts[mt][rr] += e2t;
                bs[mt][rr] += e2;
                jt += e2t;
                jb += e2;
            }
        // col-side: reduce over the 4 kq groups; each (wv,col) written once
        jt += __shfl_xor(jt, 16, 64); jt += __shfl_xor(jt, 32, 64);
        jb += __shfl_xor(jb, 16, 64); jb += __shfl_xor(jb, 32, 64);
        if (kq == 0) {
            s_jt[wv][ntl * 16 + mrow] = jt;
            s_jb[wv][ntl * 16 + mrow] = jb;
        }
    }

    // ---- loop 2: diagonal chunks (range tail), one-sided, guard i==j ----
    for (int ntl = ndch; ntl < len; ntl++) {
        LOAD_B_AND_MFMA()
        #pragma unroll
        for (int mt = 0; mt < 4; mt++)
            #pragma unroll
            for (int rr = 0; rr < 4; rr++) {
                int i = iw + mt * 16 + kq * 4 + rr;
                float d2 = fmaf(-2.0f, acc[mt][rr], sqi[mt][rr] + sqj);
                d2 = fmaxf(d2, 0.0f);
                float dist = __builtin_amdgcn_sqrtf(d2);
                float e2 = __builtin_amdgcn_exp2f(fmaf(c1, dist, SHIFT));
                bool offd = (i != jr);
                bool same = offd && (yj == ((ypack[mt] >> (8 * rr)) & 255));
                bs[mt][rr] += offd ? e2 : 0.0f;
                ts[mt][rr] += same ? e2 : 0.0f;
            }
    }
#undef LOAD_B_AND_MFMA

    // row-side: reduce across the 16 mrow lanes sharing each row, one atomic/row
    #pragma unroll
    for (int mt = 0; mt < 4; mt++)
        #pragma unroll
        for (int rr = 0; rr < 4; rr++) {
            float tv = ts[mt][rr], bv = bs[mt][rr];
            #pragma unroll
            for (int off = 1; off < 16; off <<= 1) {
                tv += __shfl_xor(tv, off, 64);
                bv += __shfl_xor(bv, off, 64);
            }
            if (mrow == 0) {
                int i = iw + mt * 16 + kq * 4 + rr;
                atomicAdd(&top[i], tv);
                atomicAdd(&bot[i], bv);
            }
        }

    // col-side drain: sum the 8 per-wave slices, one atomic per column
    if (ndch > 0) {                         // block-uniform condition
        __syncthreads();
        for (int t = tid; t < ndch * 16; t += 512) {
            float tt = 0.0f, bb = 0.0f;
            #pragma unroll
            for (int v = 0; v < 8; v++) { tt += s_jt[v][t]; bb += s_jb[v][t]; }
            atomicAdd(&top[lc0 * 16 + t], tt);
            atomicAdd(&bot[lc0 * 16 + t], bb);
        }
    }
}

__global__ __launch_bounds__(256) void snn_final(
    const float* __restrict__ top, const float* __restrict__ bot,
    float* __restrict__ out)
{
    const int i = blockIdx.x * 256 + threadIdx.x;
    float t = top[i];                    // top * 2^64, normal fp32
    float b = bot[i] * 0x1p-64f + EPS;   // bot tiny; +eps dominates
    float acc = (logf(t) - SHIFT_LN) - logf(b);
    #pragma unroll
    for (int off = 32; off > 0; off >>= 1) acc += __shfl_xor(acc, off, 64);
    __shared__ float red[4];
    if ((threadIdx.x & 63) == 0) red[threadIdx.x >> 6] = acc;
    __syncthreads();
    if (threadIdx.x == 0) {
        float s = red[0] + red[1] + red[2] + red[3];
        atomicAdd(out, -s / (float)N_ROWS);
    }
}

extern "C" void kernel_launch(void* const* d_in, const int* in_sizes, int n_in,
                              void* d_out, int out_size, void* d_ws, size_t ws_size,
                              hipStream_t stream) {
    const float* x = (const float*)d_in[0];
    const int*   y = (const int*)d_in[1];
    const float* w = (const float*)d_in[2];
    float* out = (float*)d_out;

    float* ws  = (float*)d_ws;
    float* top = ws;
    float* bot = ws + N_ROWS;
    float* sq  = ws + 2 * N_ROWS;
    _Float16* xh = (_Float16*)(ws + 3 * N_ROWS);
    _Float16* xl = xh + (size_t)N_ROWS * DIM;

    snn_prep<<<N_ROWS / 4, 256, 0, stream>>>(x, xh, xl, sq, top, bot, out);
    snn_mfma<<<TB, 512, 0, stream>>>(xh, xl, sq, y, w, top, bot);
    snn_final<<<N_ROWS / 256, 256, 0, stream>>>(top, bot, out);
}

// Round 10
// 104.114 us; speedup vs baseline: 1.8631x; 1.8631x over previous
//
#include <hip/hip_runtime.h>

typedef _Float16 f16x8 __attribute__((ext_vector_type(8)));
typedef float    f32x4 __attribute__((ext_vector_type(4)));

#define N_ROWS 8192
#define DIM 64
#define EPS 1e-8f
#define LOG2E 1.4426950408889634f
#define SHIFT 64.0f                      // exp terms scaled by 2^64
#define SHIFT_LN 44.361419555836499802f  // 64 * ln(2)
#define TILE_I 256                       // i-panel (8 waves x 32 rows, mt=2)
#define NBI (N_ROWS / TILE_I)            // 32 panels
#define TB 512                           // EXACTLY one block per CU slot
#define MAXC 17                          // max j-chunks (16 rows each) per block

// ws: top[8192] | bot[8192] | sq[8192] (f32) | xh[8192*64] | xl[8192*64] (f16)

// fused: zero top/bot/out + f16 split + row norms. one wave per row.
__global__ void snn_prep(const float* __restrict__ x, _Float16* __restrict__ xh,
                         _Float16* __restrict__ xl, float* __restrict__ sq,
                         float* __restrict__ top, float* __restrict__ bot,
                         float* __restrict__ out) {
    const int gt = blockIdx.x * 256 + threadIdx.x;
    if (gt < N_ROWS) { top[gt] = 0.0f; bot[gt] = 0.0f; }
    if (gt == 0) out[0] = 0.0f;
    const int row = gt >> 6, lane = threadIdx.x & 63;
    float v = x[row * DIM + lane];
    _Float16 h = (_Float16)v;
    _Float16 l = (_Float16)(v - (float)h);
    xh[row * DIM + lane] = h;
    xl[row * DIM + lane] = l;
    float s = v * v;
    #pragma unroll
    for (int off = 32; off > 0; off >>= 1) s += __shfl_xor(s, off, 64);
    if (lane == 0) sq[row] = s;
}

// Symmetric triangular pass, R8's proven 512-uniform-block partition
// (one scheduling round), re-bodied for 4 waves/SIMD:
//   - 8-wave (512-thread) blocks, each wave owns 32 i-rows (mt=2)
//   - per-wave regs ~100 (A 32 + ts/bs 16 + sqi 8 + acc 8 + B 16 + misc)
//     fits the (512,4) cap of 128 -> 2 blocks/CU = 16 waves/CU = 4 waves/SIMD
//   - R9 post-mortem: same bounds with the mt=4 body (~164 regs) forced a
//     64-VGPR allocation + 330MB scratch; registers were the real constraint
//   - R1's mt=2 "1.84x/pair" was mostly un-hidden B-load stall (round model);
//     doubled TLP attacks exactly that component
__global__ __launch_bounds__(512, 4) void snn_mfma(
    const _Float16* __restrict__ xh, const _Float16* __restrict__ xl,
    const float* __restrict__ sq, const int* __restrict__ y,
    const float* __restrict__ w,
    float* __restrict__ top, float* __restrict__ bot)
{
    __shared__ float s_sqj[MAXC * 16];
    __shared__ int   s_yj[MAXC * 16];
    __shared__ float s_jt[8][MAXC * 16];   // per-wave col-side top (no atomics)
    __shared__ float s_jb[8][MAXC * 16];   // per-wave col-side bot

    // ---- decode bid -> (panel bi, chunk range [c0, c0+len)) — R8 verbatim ----
    const int bid = blockIdx.x;
    int bi = 0, kk = 0, cum = 0;
    for (int p = 0; p < NBI; p++) {
        int nb = (p < 16) ? p + 1 : p;          // blocks in panel p
        if (bid < cum + nb) { bi = p; kk = bid - cum; break; }
        cum += nb;
    }
    int c0, len;
    if (bi < 16)      { c0 = 16 * kk;              len = 16; }
    else if (kk < 16) { c0 = 17 * kk;              len = 17; }
    else              { c0 = 272 + 16 * (kk - 16); len = 16; }
    const int ndch = min(max(16 * bi - c0, 0), len);  // leading non-diag chunks
    const int I0 = bi * TILE_I;

    const int tid = threadIdx.x, wv = tid >> 6, lane = tid & 63;
    const int mrow = lane & 15, kq = lane >> 4;

    for (int t = tid; t < len * 16; t += 512) {
        s_sqj[t] = sq[c0 * 16 + t];
        s_yj[t]  = y[c0 * 16 + t];
    }
    __syncthreads();

    const int iw = I0 + wv * 32;   // this wave's first i-row (32 rows, mt=2)

    // A fragments resident for the block lifetime (32 VGPRs)
    f16x8 ah[2][2], al[2][2];
    #pragma unroll
    for (int mt = 0; mt < 2; mt++)
        #pragma unroll
        for (int kc = 0; kc < 2; kc++) {
            int a = (iw + mt * 16 + mrow) * DIM + kc * 32 + kq * 8;
            ah[mt][kc] = *(const f16x8*)(xh + a);
            al[mt][kc] = *(const f16x8*)(xl + a);
        }

    // per-slot row metadata: i = iw + mt*16 + kq*4 + rr ; labels packed 4/VGPR
    float sqi[2][4]; int ypack[2];
    #pragma unroll
    for (int mt = 0; mt < 2; mt++) {
        int yp = 0;
        #pragma unroll
        for (int rr = 0; rr < 4; rr++) {
            int i = iw + mt * 16 + kq * 4 + rr;
            sqi[mt][rr] = sq[i];
            yp |= (y[i] & 255) << (8 * rr);
        }
        ypack[mt] = yp;
    }

    float ts[2][4], bs[2][4];
    #pragma unroll
    for (int mt = 0; mt < 2; mt++)
        #pragma unroll
        for (int rr = 0; rr < 4; rr++) { ts[mt][rr] = 0.0f; bs[mt][rr] = 0.0f; }

    const float c1 = -w[0] * LOG2E;

#define LOAD_B_AND_MFMA()                                                        \
    const int jr = (c0 + ntl) * 16 + mrow;        /* this lane's global j row */ \
    const int boff = jr * DIM + kq * 8;                                          \
    f16x8 cbh0 = *(const f16x8*)(xh + boff);                                     \
    f16x8 cbh1 = *(const f16x8*)(xh + boff + 32);                                \
    f16x8 cbl0 = *(const f16x8*)(xl + boff);                                     \
    f16x8 cbl1 = *(const f16x8*)(xl + boff + 32);                                \
    const float sqj = s_sqj[ntl * 16 + mrow];                                    \
    const int   yj  = s_yj[ntl * 16 + mrow];                                     \
    f32x4 acc[2];                                                                \
    acc[0] = (f32x4){0.f, 0.f, 0.f, 0.f};                                        \
    acc[1] = (f32x4){0.f, 0.f, 0.f, 0.f};                                        \
    _Pragma("unroll")                                                            \
    for (int mt = 0; mt < 2; mt++)                                               \
        acc[mt] = __builtin_amdgcn_mfma_f32_16x16x32_f16(ah[mt][0], cbh0, acc[mt], 0, 0, 0); \
    _Pragma("unroll")                                                            \
    for (int mt = 0; mt < 2; mt++)                                               \
        acc[mt] = __builtin_amdgcn_mfma_f32_16x16x32_f16(ah[mt][1], cbh1, acc[mt], 0, 0, 0); \
    _Pragma("unroll")                                                            \
    for (int mt = 0; mt < 2; mt++)                                               \
        acc[mt] = __builtin_amdgcn_mfma_f32_16x16x32_f16(ah[mt][0], cbl0, acc[mt], 0, 0, 0); \
    _Pragma("unroll")                                                            \
    for (int mt = 0; mt < 2; mt++)                                               \
        acc[mt] = __builtin_amdgcn_mfma_f32_16x16x32_f16(ah[mt][1], cbl1, acc[mt], 0, 0, 0); \
    _Pragma("unroll")                                                            \
    for (int mt = 0; mt < 2; mt++)                                               \
        acc[mt] = __builtin_amdgcn_mfma_f32_16x16x32_f16(al[mt][0], cbh0, acc[mt], 0, 0, 0); \
    _Pragma("unroll")                                                            \
    for (int mt = 0; mt < 2; mt++)                                               \
        acc[mt] = __builtin_amdgcn_mfma_f32_16x16x32_f16(al[mt][1], cbh1, acc[mt], 0, 0, 0);

    // ---- loop 1: sub-diagonal chunks, both-sided, i != j guaranteed ----
    for (int ntl = 0; ntl < ndch; ntl++) {
        LOAD_B_AND_MFMA()
        float jt = 0.0f, jb = 0.0f;
        #pragma unroll
        for (int mt = 0; mt < 2; mt++)
            #pragma unroll
            for (int rr = 0; rr < 4; rr++) {
                float d2 = fmaf(-2.0f, acc[mt][rr], sqi[mt][rr] + sqj);
                d2 = fmaxf(d2, 0.0f);
                float dist = __builtin_amdgcn_sqrtf(d2);
                float e2 = __builtin_amdgcn_exp2f(fmaf(c1, dist, SHIFT));
                float e2t = (yj == ((ypack[mt] >> (8 * rr)) & 255)) ? e2 : 0.0f;
                ts[mt][rr] += e2t;
                bs[mt][rr] += e2;
                jt += e2t;
                jb += e2;
            }
        // col-side: reduce over the 4 kq groups; each (wv,col) written once
        jt += __shfl_xor(jt, 16, 64); jt += __shfl_xor(jt, 32, 64);
        jb += __shfl_xor(jb, 16, 64); jb += __shfl_xor(jb, 32, 64);
        if (kq == 0) {
            s_jt[wv][ntl * 16 + mrow] = jt;
            s_jb[wv][ntl * 16 + mrow] = jb;
        }
    }

    // ---- loop 2: diagonal chunks (range tail), one-sided, guard i==j ----
    for (int ntl = ndch; ntl < len; ntl++) {
        LOAD_B_AND_MFMA()
        #pragma unroll
        for (int mt = 0; mt < 2; mt++)
            #pragma unroll
            for (int rr = 0; rr < 4; rr++) {
                int i = iw + mt * 16 + kq * 4 + rr;
                float d2 = fmaf(-2.0f, acc[mt][rr], sqi[mt][rr] + sqj);
                d2 = fmaxf(d2, 0.0f);
                float dist = __builtin_amdgcn_sqrtf(d2);
                float e2 = __builtin_amdgcn_exp2f(fmaf(c1, dist, SHIFT));
                bool offd = (i != jr);
                bool same = offd && (yj == ((ypack[mt] >> (8 * rr)) & 255));
                bs[mt][rr] += offd ? e2 : 0.0f;
                ts[mt][rr] += same ? e2 : 0.0f;
            }
    }
#undef LOAD_B_AND_MFMA

    // row-side: reduce across the 16 mrow lanes sharing each row, one atomic/row
    #pragma unroll
    for (int mt = 0; mt < 2; mt++)
        #pragma unroll
        for (int rr = 0; rr < 4; rr++) {
            float tv = ts[mt][rr], bv = bs[mt][rr];
            #pragma unroll
            for (int off = 1; off < 16; off <<= 1) {
                tv += __shfl_xor(tv, off, 64);
                bv += __shfl_xor(bv, off, 64);
            }
            if (mrow == 0) {
                int i = iw + mt * 16 + kq * 4 + rr;
                atomicAdd(&top[i], tv);
                atomicAdd(&bot[i], bv);
            }
        }

    // col-side drain: sum the 8 per-wave slices, one atomic per column
    if (ndch > 0) {                         // block-uniform condition
        __syncthreads();
        for (int t = tid; t < ndch * 16; t += 512) {
            float tt = 0.0f, bb = 0.0f;
            #pragma unroll
            for (int v = 0; v < 8; v++) { tt += s_jt[v][t]; bb += s_jb[v][t]; }
            atomicAdd(&top[c0 * 16 + t], tt);
            atomicAdd(&bot[c0 * 16 + t], bb);
        }
    }
}

__global__ __launch_bounds__(256) void snn_final(
    const float* __restrict__ top, const float* __restrict__ bot,
    float* __restrict__ out)
{
    const int i = blockIdx.x * 256 + threadIdx.x;
    float t = top[i];                    // top * 2^64, normal fp32
    float b = bot[i] * 0x1p-64f + EPS;   // bot tiny; +eps dominates
    float acc = (logf(t) - SHIFT_LN) - logf(b);
    #pragma unroll
    for (int off = 32; off > 0; off >>= 1) acc += __shfl_xor(acc, off, 64);
    __shared__ float red[4];
    if ((threadIdx.x & 63) == 0) red[threadIdx.x >> 6] = acc;
    __syncthreads();
    if (threadIdx.x == 0) {
        float s = red[0] + red[1] + red[2] + red[3];
        atomicAdd(out, -s / (float)N_ROWS);
    }
}

extern "C" void kernel_launch(void* const* d_in, const int* in_sizes, int n_in,
                              void* d_out, int out_size, void* d_ws, size_t ws_size,
                              hipStream_t stream) {
    const float* x = (const float*)d_in[0];
    const int*   y = (const int*)d_in[1];
    const float* w = (const float*)d_in[2];
    float* out = (float*)d_out;

    float* ws  = (float*)d_ws;
    float* top = ws;
    float* bot = ws + N_ROWS;
    float* sq  = ws + 2 * N_ROWS;
    _Float16* xh = (_Float16*)(ws + 3 * N_ROWS);
    _Float16* xl = xh + (size_t)N_ROWS * DIM;

    snn_prep<<<N_ROWS / 4, 256, 0, stream>>>(x, xh, xl, sq, top, bot, out);
    snn_mfma<<<TB, 512, 0, stream>>>(xh, xl, sq, y, w, top, bot);
    snn_final<<<N_ROWS / 256, 256, 0, stream>>>(top, bot, out);
}

// Round 11
// 94.728 us; speedup vs baseline: 2.0477x; 1.0991x over previous
//
#include <hip/hip_runtime.h>

typedef _Float16 f16x8 __attribute__((ext_vector_type(8)));
typedef float    f32x4 __attribute__((ext_vector_type(4)));

#define N_ROWS 8192
#define DIM 64
#define EPS 1e-8f
#define LOG2E 1.4426950408889634f
#define SHIFT 64.0f                      // exp terms scaled by 2^64
#define SHIFT_LN 44.361419555836499802f  // 64 * ln(2)
#define TILE_I 256                       // i-panel (4 waves x 64 rows, mt=4)
#define NBI (N_ROWS / TILE_I)            // 32 panels
#define TB 512                           // EXACTLY one block per CU slot
#define MAXC 17                          // max j-chunks (16 rows each) per block

// ws: top[8192] | bot[8192] | sq[8192] (f32) | xh[8192*64] | xl[8192*64] (f16)

// fused: zero top/bot/out + f16 split + row norms. one wave per row.
__global__ void snn_prep(const float* __restrict__ x, _Float16* __restrict__ xh,
                         _Float16* __restrict__ xl, float* __restrict__ sq,
                         float* __restrict__ top, float* __restrict__ bot,
                         float* __restrict__ out) {
    const int gt = blockIdx.x * 256 + threadIdx.x;
    if (gt < N_ROWS) { top[gt] = 0.0f; bot[gt] = 0.0f; }
    if (gt == 0) out[0] = 0.0f;
    const int row = gt >> 6, lane = threadIdx.x & 63;
    float v = x[row * DIM + lane];
    _Float16 h = (_Float16)v;
    _Float16 l = (_Float16)(v - (float)h);
    xh[row * DIM + lane] = h;
    xl[row * DIM + lane] = l;
    float s = v * v;
    #pragma unroll
    for (int off = 32; off > 0; off >>= 1) s += __shfl_xor(s, off, 64);
    if (lane == 0) sq[row] = s;
}

// Symmetric triangular pass, R8 partition (512 uniform blocks, ONE scheduling
// round) and R8 body (mt=4, (256,2)), with TWO j-chunks per loop iteration:
//   - R10 falsified the TLP theory (4 waves/SIMD, zero spill, same 41-46us,
//     issue-busy stuck at ~41%): the bound is serial latency PER ITERATION
//     (~6K cyc wall vs ~500 issue), not wave count.
//   - 2-wide iterations issue 8 B-loads together (MLP 4->8) and halve the
//     number of serial segments per block: 17 -> 9.
//   - NOT the R3/R5 prefetch trap: no cross-iteration loads, no wrap-around;
//     a plain wider body the compiler schedules itself.
//   - acc reused across the two chunks (MFMA+epilogue A, then B).
__global__ __launch_bounds__(256, 2) void snn_mfma(
    const _Float16* __restrict__ xh, const _Float16* __restrict__ xl,
    const float* __restrict__ sq, const int* __restrict__ y,
    const float* __restrict__ w,
    float* __restrict__ top, float* __restrict__ bot)
{
    __shared__ float s_sqj[MAXC * 16];
    __shared__ int   s_yj[MAXC * 16];
    __shared__ float s_jt[4][MAXC * 16];   // per-wave col-side top (no atomics)
    __shared__ float s_jb[4][MAXC * 16];   // per-wave col-side bot

    // ---- decode bid -> (panel bi, chunk range [c0, c0+len)) — R8 verbatim ----
    const int bid = blockIdx.x;
    int bi = 0, kk = 0, cum = 0;
    for (int p = 0; p < NBI; p++) {
        int nb = (p < 16) ? p + 1 : p;          // blocks in panel p
        if (bid < cum + nb) { bi = p; kk = bid - cum; break; }
        cum += nb;
    }
    int c0, len;
    if (bi < 16)      { c0 = 16 * kk;              len = 16; }
    else if (kk < 16) { c0 = 17 * kk;              len = 17; }
    else              { c0 = 272 + 16 * (kk - 16); len = 16; }
    const int ndch = min(max(16 * bi - c0, 0), len);  // leading non-diag chunks
    const int I0 = bi * TILE_I;

    const int tid = threadIdx.x, wv = tid >> 6, lane = tid & 63;
    const int mrow = lane & 15, kq = lane >> 4;

    for (int t = tid; t < len * 16; t += 256) {
        s_sqj[t] = sq[c0 * 16 + t];
        s_yj[t]  = y[c0 * 16 + t];
    }
    __syncthreads();

    const int iw = I0 + wv * 64;   // this wave's first i-row

    // A fragments resident for the block lifetime (64 VGPRs)
    f16x8 ah[4][2], al[4][2];
    #pragma unroll
    for (int mt = 0; mt < 4; mt++)
        #pragma unroll
        for (int kc = 0; kc < 2; kc++) {
            int a = (iw + mt * 16 + mrow) * DIM + kc * 32 + kq * 8;
            ah[mt][kc] = *(const f16x8*)(xh + a);
            al[mt][kc] = *(const f16x8*)(xl + a);
        }

    // per-slot row metadata: i = iw + mt*16 + kq*4 + rr ; labels packed 4/VGPR
    float sqi[4][4]; int ypack[4];
    #pragma unroll
    for (int mt = 0; mt < 4; mt++) {
        int yp = 0;
        #pragma unroll
        for (int rr = 0; rr < 4; rr++) {
            int i = iw + mt * 16 + kq * 4 + rr;
            sqi[mt][rr] = sq[i];
            yp |= (y[i] & 255) << (8 * rr);
        }
        ypack[mt] = yp;
    }

    float ts[4][4], bs[4][4];
    #pragma unroll
    for (int mt = 0; mt < 4; mt++)
        #pragma unroll
        for (int rr = 0; rr < 4; rr++) { ts[mt][rr] = 0.0f; bs[mt][rr] = 0.0f; }

    const float c1 = -w[0] * LOG2E;
    f32x4 acc[4];

// declare + issue loads for one chunk (suffix N), chunk index NTL
#define DECL_LOAD(N, NTL)                                                        \
    const int jr##N = (c0 + (NTL)) * 16 + mrow;                                  \
    const int boff##N = jr##N * DIM + kq * 8;                                    \
    f16x8 cbh0##N = *(const f16x8*)(xh + boff##N);                               \
    f16x8 cbh1##N = *(const f16x8*)(xh + boff##N + 32);                          \
    f16x8 cbl0##N = *(const f16x8*)(xl + boff##N);                               \
    f16x8 cbl1##N = *(const f16x8*)(xl + boff##N + 32);                          \
    const float sqj##N = s_sqj[(NTL) * 16 + mrow];                               \
    const int   yj##N  = s_yj[(NTL) * 16 + mrow];

#define DO_MFMA(N)                                                               \
    _Pragma("unroll")                                                            \
    for (int mt = 0; mt < 4; mt++) acc[mt] = (f32x4){0.f, 0.f, 0.f, 0.f};        \
    _Pragma("unroll")                                                            \
    for (int mt = 0; mt < 4; mt++)                                               \
        acc[mt] = __builtin_amdgcn_mfma_f32_16x16x32_f16(ah[mt][0], cbh0##N, acc[mt], 0, 0, 0); \
    _Pragma("unroll")                                                            \
    for (int mt = 0; mt < 4; mt++)                                               \
        acc[mt] = __builtin_amdgcn_mfma_f32_16x16x32_f16(ah[mt][1], cbh1##N, acc[mt], 0, 0, 0); \
    _Pragma("unroll")                                                            \
    for (int mt = 0; mt < 4; mt++)                                               \
        acc[mt] = __builtin_amdgcn_mfma_f32_16x16x32_f16(ah[mt][0], cbl0##N, acc[mt], 0, 0, 0); \
    _Pragma("unroll")                                                            \
    for (int mt = 0; mt < 4; mt++)                                               \
        acc[mt] = __builtin_amdgcn_mfma_f32_16x16x32_f16(ah[mt][1], cbl1##N, acc[mt], 0, 0, 0); \
    _Pragma("unroll")                                                            \
    for (int mt = 0; mt < 4; mt++)                                               \
        acc[mt] = __builtin_amdgcn_mfma_f32_16x16x32_f16(al[mt][0], cbh0##N, acc[mt], 0, 0, 0); \
    _Pragma("unroll")                                                            \
    for (int mt = 0; mt < 4; mt++)                                               \
        acc[mt] = __builtin_amdgcn_mfma_f32_16x16x32_f16(al[mt][1], cbh1##N, acc[mt], 0, 0, 0);

#define EPI_BOTH(N, NTL)                                                         \
    {                                                                            \
        float jt = 0.0f, jb = 0.0f;                                              \
        _Pragma("unroll")                                                        \
        for (int mt = 0; mt < 4; mt++)                                           \
            _Pragma("unroll")                                                    \
            for (int rr = 0; rr < 4; rr++) {                                     \
                float d2 = fmaf(-2.0f, acc[mt][rr], sqi[mt][rr] + sqj##N);       \
                d2 = fmaxf(d2, 0.0f);                                            \
                float dist = __builtin_amdgcn_sqrtf(d2);                         \
                float e2 = __builtin_amdgcn_exp2f(fmaf(c1, dist, SHIFT));        \
                float e2t = (yj##N == ((ypack[mt] >> (8 * rr)) & 255)) ? e2 : 0.0f; \
                ts[mt][rr] += e2t;                                               \
                bs[mt][rr] += e2;                                                \
                jt += e2t;                                                       \
                jb += e2;                                                        \
            }                                                                    \
        jt += __shfl_xor(jt, 16, 64); jt += __shfl_xor(jt, 32, 64);              \
        jb += __shfl_xor(jb, 16, 64); jb += __shfl_xor(jb, 32, 64);              \
        if (kq == 0) {                                                           \
            s_jt[wv][(NTL) * 16 + mrow] = jt;                                    \
            s_jb[wv][(NTL) * 16 + mrow] = jb;                                    \
        }                                                                        \
    }

#define EPI_DIAG(N, NTL)                                                         \
    {                                                                            \
        _Pragma("unroll")                                                        \
        for (int mt = 0; mt < 4; mt++)                                           \
            _Pragma("unroll")                                                    \
            for (int rr = 0; rr < 4; rr++) {                                     \
                int i = iw + mt * 16 + kq * 4 + rr;                              \
                float d2 = fmaf(-2.0f, acc[mt][rr], sqi[mt][rr] + sqj##N);       \
                d2 = fmaxf(d2, 0.0f);                                            \
                float dist = __builtin_amdgcn_sqrtf(d2);                         \
                float e2 = __builtin_amdgcn_exp2f(fmaf(c1, dist, SHIFT));        \
                bool offd = (i != jr##N);                                        \
                bool same = offd && (yj##N == ((ypack[mt] >> (8 * rr)) & 255));  \
                bs[mt][rr] += offd ? e2 : 0.0f;                                  \
                ts[mt][rr] += same ? e2 : 0.0f;                                  \
            }                                                                    \
    }

    int ntl = 0;
    // ---- both-sided chunks, 2-wide ----
    for (; ntl + 2 <= ndch; ntl += 2) {
        DECL_LOAD(0, ntl)
        DECL_LOAD(1, ntl + 1)
        DO_MFMA(0)
        EPI_BOTH(0, ntl)
        DO_MFMA(1)
        EPI_BOTH(1, ntl + 1)
    }
    // ---- both-sided remainder (0 or 1) ----
    for (; ntl < ndch; ntl++) {
        DECL_LOAD(0, ntl)
        DO_MFMA(0)
        EPI_BOTH(0, ntl)
    }
    // ---- diagonal chunks, 2-wide ----
    for (; ntl + 2 <= len; ntl += 2) {
        DECL_LOAD(0, ntl)
        DECL_LOAD(1, ntl + 1)
        DO_MFMA(0)
        EPI_DIAG(0, ntl)
        DO_MFMA(1)
        EPI_DIAG(1, ntl + 1)
    }
    // ---- diagonal remainder (0 or 1) ----
    for (; ntl < len; ntl++) {
        DECL_LOAD(0, ntl)
        DO_MFMA(0)
        EPI_DIAG(0, ntl)
    }
#undef DECL_LOAD
#undef DO_MFMA
#undef EPI_BOTH
#undef EPI_DIAG

    // row-side: reduce across the 16 mrow lanes sharing each row, one atomic/row
    #pragma unroll
    for (int mt = 0; mt < 4; mt++)
        #pragma unroll
        for (int rr = 0; rr < 4; rr++) {
            float tv = ts[mt][rr], bv = bs[mt][rr];
            #pragma unroll
            for (int off = 1; off < 16; off <<= 1) {
                tv += __shfl_xor(tv, off, 64);
                bv += __shfl_xor(bv, off, 64);
            }
            if (mrow == 0) {
                int i = iw + mt * 16 + kq * 4 + rr;
                atomicAdd(&top[i], tv);
                atomicAdd(&bot[i], bv);
            }
        }

    // col-side drain: sum the 4 per-wave slices, one atomic per column
    if (ndch > 0) {                         // block-uniform condition
        __syncthreads();
        for (int t = tid; t < ndch * 16; t += 256) {
            float tt = s_jt[0][t] + s_jt[1][t] + s_jt[2][t] + s_jt[3][t];
            float bb = s_jb[0][t] + s_jb[1][t] + s_jb[2][t] + s_jb[3][t];
            atomicAdd(&top[c0 * 16 + t], tt);
            atomicAdd(&bot[c0 * 16 + t], bb);
        }
    }
}

__global__ __launch_bounds__(256) void snn_final(
    const float* __restrict__ top, const float* __restrict__ bot,
    float* __restrict__ out)
{
    const int i = blockIdx.x * 256 + threadIdx.x;
    float t = top[i];                    // top * 2^64, normal fp32
    float b = bot[i] * 0x1p-64f + EPS;   // bot tiny; +eps dominates
    float acc = (logf(t) - SHIFT_LN) - logf(b);
    #pragma unroll
    for (int off = 32; off > 0; off >>= 1) acc += __shfl_xor(acc, off, 64);
    __shared__ float red[4];
    if ((threadIdx.x & 63) == 0) red[threadIdx.x >> 6] = acc;
    __syncthreads();
    if (threadIdx.x == 0) {
        float s = red[0] + red[1] + red[2] + red[3];
        atomicAdd(out, -s / (float)N_ROWS);
    }
}

extern "C" void kernel_launch(void* const* d_in, const int* in_sizes, int n_in,
                              void* d_out, int out_size, void* d_ws, size_t ws_size,
                              hipStream_t stream) {
    const float* x = (const float*)d_in[0];
    const int*   y = (const int*)d_in[1];
    const float* w = (const float*)d_in[2];
    float* out = (float*)d_out;

    float* ws  = (float*)d_ws;
    float* top = ws;
    float* bot = ws + N_ROWS;
    float* sq  = ws + 2 * N_ROWS;
    _Float16* xh = (_Float16*)(ws + 3 * N_ROWS);
    _Float16* xl = xh + (size_t)N_ROWS * DIM;

    snn_prep<<<N_ROWS / 4, 256, 0, stream>>>(x, xh, xl, sq, top, bot, out);
    snn_mfma<<<TB, 256, 0, stream>>>(xh, xl, sq, y, w, top, bot);
    snn_final<<<N_ROWS / 256, 256, 0, stream>>>(top, bot, out);
}